// Round 4
// baseline (373.045 us; speedup 1.0000x reference)
//
#include <hip/hip_runtime.h>
#include <hip/hip_bf16.h>
#include <math.h>

constexpr int F = 128;        // in features
constexpr int H = 64;         // out features
constexpr int NB = 32;        // nodes per gemm block
constexpr int XS_STRIDE = F + 4;
constexpr int NCH = 256;      // edge chunks (pass-A blocks)
constexpr int SHIFT = 7;      // log2(nodes per bucket)
constexpr int BWID = 1 << SHIFT;   // 128 nodes per bucket
constexpr int MAXBUK = 512;   // >= nbuk = ceil(N/128) = 391

__device__ __forceinline__ float blo(unsigned u) { return __uint_as_float(u << 16); }
__device__ __forceinline__ float bhi(unsigned u) { return __uint_as_float(u & 0xffff0000u); }

// ---- pass A1: per-chunk bucket histogram (LDS) + per-edge rank -------------
__global__ __launch_bounds__(1024) void kA_hist(const int* __restrict__ dst,
                                                int* __restrict__ counts,
                                                unsigned short* __restrict__ rank,
                                                int E, int chsz, int nbuk) {
  __shared__ unsigned lh[MAXBUK];
  const int b = blockIdx.x, t = threadIdx.x;
  for (int i = t; i < nbuk; i += 1024) lh[i] = 0u;
  __syncthreads();
  const int e0 = b * chsz, e1 = min(e0 + chsz, E);
  for (int e = e0 + t; e < e1; e += 1024) {
    int d = dst[e];
    rank[e] = (unsigned short)atomicAdd(&lh[d >> SHIFT], 1u);  // rank < 6250
  }
  __syncthreads();
  for (int i = t; i < nbuk; i += 1024) counts[(size_t)i * NCH + b] = (int)lh[i];
}

// ---- pass A2: exclusive scan of counts (bucket-major, chunk-minor) ---------
__global__ __launch_bounds__(1024) void kA_scan(int* __restrict__ counts, int M) {
  __shared__ int buf[1024];
  const int t = threadIdx.x;
  const int seg = (M + 1023) / 1024;
  const int lo = t * seg, hi = min(lo + seg, M);
  int s = 0;
  for (int i = lo; i < hi; ++i) s += counts[i];
  buf[t] = s;
  __syncthreads();
  for (int off = 1; off < 1024; off <<= 1) {
    int a = (t >= off) ? buf[t - off] : 0;
    __syncthreads();
    buf[t] += a;
    __syncthreads();
  }
  int run = buf[t] - s;                       // exclusive over threads
  for (int i = lo; i < hi; ++i) {
    int c = counts[i];
    counts[i] = run;
    run += c;
  }
}

// ---- pass A3: scatter records into bucket-contiguous regions ---------------
// Each (chunk,bucket) segment written by exactly ONE block => writes to a
// sector are temporally clustered on one XCD => L2 merges to full sectors.
__global__ __launch_bounds__(1024) void kA_scat(const int* __restrict__ src,
                                                const int* __restrict__ dst,
                                                const float* __restrict__ w,
                                                const unsigned short* __restrict__ rank,
                                                const int* __restrict__ counts,
                                                unsigned long long* __restrict__ rec,
                                                unsigned char* __restrict__ dl,
                                                int E, int chsz, int nbuk) {
  __shared__ int lh[MAXBUK];
  const int b = blockIdx.x, t = threadIdx.x;
  for (int i = t; i < nbuk; i += 1024) lh[i] = counts[(size_t)i * NCH + b];
  __syncthreads();
  const int e0 = b * chsz, e1 = min(e0 + chsz, E);
  for (int e = e0 + t; e < e1; e += 1024) {
    int d = dst[e];
    int pos = lh[d >> SHIFT] + (int)rank[e];
    rec[pos] = ((unsigned long long)(unsigned)__float_as_int(w[e]) << 32) |
               (unsigned)src[e];
    dl[pos] = (unsigned char)(d & (BWID - 1));
  }
}

// ---- pass B: per-bucket counting sort in LDS -> final CSR + cnt/cursor/dinv
__global__ __launch_bounds__(1024) void kB_sort(const unsigned long long* __restrict__ rec,
                                                const unsigned char* __restrict__ dl,
                                                const int* __restrict__ counts,
                                                unsigned long long* __restrict__ sorted,
                                                int* __restrict__ cnt,
                                                int* __restrict__ cursor,
                                                float* __restrict__ dinv,
                                                int E, int nbuk, int N) {
  __shared__ unsigned h[BWID];
  __shared__ unsigned pf[BWID];
  __shared__ unsigned cur[BWID];
  __shared__ float dg[BWID];
  const int B = blockIdx.x, t = threadIdx.x;
  const int bb = counts[(size_t)B * NCH];
  const int be = (B + 1 < nbuk) ? counts[(size_t)(B + 1) * NCH] : E;
  if (t < BWID) { h[t] = 0u; dg[t] = 0.0f; }
  __syncthreads();
  for (int i = bb + t; i < be; i += 1024) atomicAdd(&h[dl[i]], 1u);
  __syncthreads();
  if (t < BWID) pf[t] = h[t];
  __syncthreads();
  for (int off = 1; off < BWID; off <<= 1) {
    unsigned a = (t >= off && t < BWID) ? pf[t - off] : 0u;
    __syncthreads();
    if (t < BWID) pf[t] += a;
    __syncthreads();
  }
  if (t < BWID) cur[t] = pf[t] - h[t];       // exclusive prefix
  __syncthreads();
  for (int i = bb + t; i < be; i += 1024) {
    unsigned long long r = rec[i];
    int d = dl[i];
    unsigned pos = atomicAdd(&cur[d], 1u);
    sorted[(size_t)bb + pos] = r;            // 32 KB window, one XCD: merges
    atomicAdd(&dg[d], __uint_as_float((unsigned)(r >> 32)));
  }
  __syncthreads();
  const int node = (B << SHIFT) + t;
  if (t < BWID && node < N) {
    cnt[node] = (int)h[t];
    cursor[node] = bb + (int)(pf[t] - h[t]);
    dinv[node] = rsqrtf(1.0f + dg[t]);       // +1 = self loop weight
  }
}

// ---------------- h = x @ W, output bf16 (N x 128)@(128 x 64) ---------------
__global__ __launch_bounds__(256) void k_gemm(const float* __restrict__ x,
                                              const float* __restrict__ W,
                                              unsigned short* __restrict__ hb, int N) {
  __shared__ float Ws[F * H];
  __shared__ float xs[NB * XS_STRIDE];
  const int t = threadIdx.x;
  {
    const float4* W4 = (const float4*)W;
    float4* Ws4 = (float4*)Ws;
#pragma unroll
    for (int i = 0; i < (F * H / 4) / 256; ++i) Ws4[t + i * 256] = W4[t + i * 256];
  }
  const int node0 = blockIdx.x * NB;
  {
    const float4* x4 = (const float4*)(x + (size_t)node0 * F);
    int lim = (N - node0 < NB ? N - node0 : NB) * (F / 4);
    for (int i = t; i < NB * (F / 4); i += 256) {
      int nl = i / (F / 4), kk = i % (F / 4);
      float4 v = (i < lim) ? x4[i] : make_float4(0.f, 0.f, 0.f, 0.f);
      *(float4*)&xs[nl * XS_STRIDE + kk * 4] = v;
    }
  }
  __syncthreads();
  const int f0 = (t & 15) * 4;
  const int nl0 = (t >> 4) * 2;
  float acc[2][4] = {};
  for (int k = 0; k < F; k += 4) {
    float xr[2][4];
    float wr[4][4];
    *(float4*)&xr[0][0] = *(const float4*)&xs[(nl0 + 0) * XS_STRIDE + k];
    *(float4*)&xr[1][0] = *(const float4*)&xs[(nl0 + 1) * XS_STRIDE + k];
#pragma unroll
    for (int i = 0; i < 4; ++i)
      *(float4*)&wr[i][0] = *(const float4*)&Ws[(k + i) * H + f0];
#pragma unroll
    for (int i = 0; i < 4; ++i)
#pragma unroll
      for (int n = 0; n < 2; ++n)
#pragma unroll
        for (int j = 0; j < 4; ++j)
          acc[n][j] += xr[n][i] * wr[i][j];
  }
#pragma unroll
  for (int n = 0; n < 2; ++n) {
    int node = node0 + nl0 + n;
    if (node < N) {
      ushort4 o;
      o.x = __bfloat16_as_ushort(__float2bfloat16(acc[n][0]));
      o.y = __bfloat16_as_ushort(__float2bfloat16(acc[n][1]));
      o.z = __bfloat16_as_ushort(__float2bfloat16(acc[n][2]));
      o.w = __bfloat16_as_ushort(__float2bfloat16(acc[n][3]));
      *(ushort4*)&hb[(size_t)node * H + f0] = o;
    }
  }
}

// ---- gather-aggregate (bf16 h) + fused relu·dot: 16 lanes/node, 4 nodes/wave
__global__ __launch_bounds__(256) void k_agg(const int2* __restrict__ sorted,
                                             const int* __restrict__ cursor,
                                             const int* __restrict__ cnt,
                                             const float* __restrict__ dinv,
                                             const unsigned short* __restrict__ hb,
                                             const float* __restrict__ b,
                                             const float* __restrict__ fcw,
                                             float* __restrict__ partials, int N) {
  const int wid = threadIdx.x >> 6;
  const int lane = threadIdx.x & 63;
  const int seg = lane >> 4;        // 0..3: node segment within wave
  const int sl = lane & 15;         // lane within segment: 16 x 4 feats
  const int n = blockIdx.x * 16 + wid * 4 + seg;
  float p = 0.0f;
  if (n < N) {
    float dn = dinv[n];
    uint2 rn = *(const uint2*)(hb + ((size_t)n << 6) + (sl << 2));
    float4 bb = ((const float4*)b)[sl];
    float dn2 = dn * dn;
    float ax = bb.x + dn2 * blo(rn.x);
    float ay = bb.y + dn2 * bhi(rn.x);
    float az = bb.z + dn2 * blo(rn.y);
    float aw = bb.w + dn2 * bhi(rn.y);
    int e = cursor[n];
    int end = e + cnt[n];
    for (; e + 1 < end; e += 2) {
      int2 e0 = sorted[e];
      int2 e1 = sorted[e + 1];
      float dv0 = dinv[e0.x];
      float dv1 = dinv[e1.x];
      uint2 r0 = *(const uint2*)(hb + ((size_t)e0.x << 6) + (sl << 2));
      uint2 r1 = *(const uint2*)(hb + ((size_t)e1.x << 6) + (sl << 2));
      float n0 = dn * dv0 * __int_as_float(e0.y);
      float n1 = dn * dv1 * __int_as_float(e1.y);
      ax += n0 * blo(r0.x) + n1 * blo(r1.x);
      ay += n0 * bhi(r0.x) + n1 * bhi(r1.x);
      az += n0 * blo(r0.y) + n1 * blo(r1.y);
      aw += n0 * bhi(r0.y) + n1 * bhi(r1.y);
    }
    if (e < end) {
      int2 e0 = sorted[e];
      float dv0 = dinv[e0.x];
      uint2 r0 = *(const uint2*)(hb + ((size_t)e0.x << 6) + (sl << 2));
      float n0 = dn * dv0 * __int_as_float(e0.y);
      ax += n0 * blo(r0.x);
      ay += n0 * bhi(r0.x);
      az += n0 * blo(r0.y);
      aw += n0 * bhi(r0.y);
    }
    float4 fw = ((const float4*)fcw)[(size_t)n * 16 + sl];
    p = fmaxf(ax, 0.f) * fw.x + fmaxf(ay, 0.f) * fw.y +
        fmaxf(az, 0.f) * fw.z + fmaxf(aw, 0.f) * fw.w;
  }
  p += __shfl_down(p, 8);
  p += __shfl_down(p, 4);
  p += __shfl_down(p, 2);
  p += __shfl_down(p, 1);
  __shared__ float ls[16];
  if (sl == 0) ls[wid * 4 + seg] = p;
  __syncthreads();
  if (threadIdx.x == 0) {
    float s = 0.f;
#pragma unroll
    for (int i = 0; i < 16; ++i) s += ls[i];
    partials[blockIdx.x] = s;
  }
}

// ---------------- final: sum partials, + fc_b, sigmoid ----------------------
__global__ __launch_bounds__(1024) void k_fred(const float* __restrict__ partials,
                                               int M,
                                               const float* __restrict__ fcb,
                                               float* __restrict__ out) {
  const int t = threadIdx.x;
  float s = 0.0f;
  for (int i = t; i < M; i += 1024) s += partials[i];
#pragma unroll
  for (int off = 32; off > 0; off >>= 1) s += __shfl_down(s, off);
  __shared__ float ls[16];
  if ((t & 63) == 0) ls[t >> 6] = s;
  __syncthreads();
  if (t == 0) {
    float tot = 0.0f;
#pragma unroll
    for (int i = 0; i < 16; ++i) tot += ls[i];
    float logit = tot + fcb[0];
    out[0] = 1.0f / (1.0f + expf(-logit));
  }
}

extern "C" void kernel_launch(void* const* d_in, const int* in_sizes, int n_in,
                              void* d_out, int out_size, void* d_ws, size_t ws_size,
                              hipStream_t stream) {
  const float* x      = (const float*)d_in[0];
  const int*   elist  = (const int*)d_in[1];
  const float* eattr  = (const float*)d_in[2];
  const float* conv_w = (const float*)d_in[3];
  const float* conv_b = (const float*)d_in[4];
  const float* fc_w   = (const float*)d_in[5];
  const float* fc_b   = (const float*)d_in[6];
  float* out = (float*)d_out;

  const int N = in_sizes[0] / F;   // 50000
  const int E = in_sizes[2];       // 1,600,000
  const int* src = elist;
  const int* dst = elist + E;

  const int chsz = (E + NCH - 1) / NCH;        // 6250
  const int nbuk = ((N - 1) >> SHIFT) + 1;     // 391
  const int M = nbuk * NCH;                    // 100096

  char* wsb = (char*)d_ws;
  unsigned long long* sorted = (unsigned long long*)wsb;       // E*8
  unsigned long long* rec = sorted + E;                        // E*8
  int*   counts = (int*)(rec + E);                             // M*4
  int*   cnt    = counts + M;                                  // N*4
  int*   cursor = cnt + N;                                     // N*4
  float* dinv   = (float*)(cursor + N);                        // N*4
  const int nAgg = (N + 15) / 16;
  float* partials = dinv + N;                                  // nAgg*4
  unsigned short* rank = (unsigned short*)(partials + nAgg);   // E*2
  unsigned short* hb = rank + E;                               // N*H*2
  unsigned char* dl = (unsigned char*)(hb + (size_t)N * H);    // E*1

  kA_hist<<<NCH, 1024, 0, stream>>>(dst, counts, rank, E, chsz, nbuk);
  kA_scan<<<1, 1024, 0, stream>>>(counts, M);
  kA_scat<<<NCH, 1024, 0, stream>>>(src, dst, eattr, rank, counts, rec, dl, E,
                                    chsz, nbuk);
  kB_sort<<<nbuk, 1024, 0, stream>>>(rec, dl, counts, sorted, cnt, cursor, dinv,
                                     E, nbuk, N);
  k_gemm<<<(N + NB - 1) / NB, 256, 0, stream>>>(x, conv_w, hb, N);
  k_agg<<<nAgg, 256, 0, stream>>>((const int2*)sorted, cursor, cnt, dinv, hb,
                                  conv_b, fc_w, partials, N);
  k_fred<<<1, 1024, 0, stream>>>(partials, nAgg, fc_b, out);
}

// Round 5
// 216.188 us; speedup vs baseline: 1.7256x; 1.7256x over previous
//
#include <hip/hip_runtime.h>
#include <hip/hip_bf16.h>
#include <math.h>

constexpr int F = 128;        // in features
constexpr int H = 64;         // out features
constexpr int NB = 32;        // nodes per gemm block
constexpr int XS_STRIDE = F + 4;
constexpr int NCH = 256;      // edge chunks (pass-A blocks)
constexpr int SHIFT = 7;      // log2(nodes per bucket)
constexpr int BWID = 1 << SHIFT;   // 128 nodes per bucket
constexpr int MAXBUK = 512;   // >= nbuk = ceil(N/128) = 391

__device__ __forceinline__ float blo(unsigned u) { return __uint_as_float(u << 16); }
__device__ __forceinline__ float bhi(unsigned u) { return __uint_as_float(u & 0xffff0000u); }

// ---- pass A1: per-chunk bucket histogram (LDS) + per-edge rank -------------
__global__ __launch_bounds__(1024) void kA_hist(const int* __restrict__ dst,
                                                int* __restrict__ counts,
                                                unsigned short* __restrict__ rank,
                                                int E, int chsz, int nbuk) {
  __shared__ unsigned lh[MAXBUK];
  const int b = blockIdx.x, t = threadIdx.x;
  for (int i = t; i < nbuk; i += 1024) lh[i] = 0u;
  __syncthreads();
  const int e0 = b * chsz, e1 = min(e0 + chsz, E);
  for (int e = e0 + t; e < e1; e += 1024) {
    int d = dst[e];
    rank[e] = (unsigned short)atomicAdd(&lh[d >> SHIFT], 1u);  // rank < 6250
  }
  __syncthreads();
  for (int i = t; i < nbuk; i += 1024) counts[(size_t)i * NCH + b] = (int)lh[i];
}

// ---- pass A2a: parallel exclusive scan, phase 1 (block-local + block sums) --
__global__ __launch_bounds__(1024) void kS1(int* __restrict__ counts,
                                            int* __restrict__ bsum, int M) {
  __shared__ int buf[1024];
  const int t = threadIdx.x;
  const int i = blockIdx.x * 1024 + t;
  int v = (i < M) ? counts[i] : 0;
  buf[t] = v;
  __syncthreads();
  for (int off = 1; off < 1024; off <<= 1) {
    int a = (t >= off) ? buf[t - off] : 0;
    __syncthreads();
    buf[t] += a;
    __syncthreads();
  }
  if (i < M) counts[i] = buf[t] - v;          // exclusive, block-local
  if (t == 1023) bsum[blockIdx.x] = buf[t];
}

// ---- pass A2b: add prefix of block sums (<=98 blocks, inline loop) ---------
__global__ __launch_bounds__(1024) void kS2(int* __restrict__ counts,
                                            const int* __restrict__ bsum, int M) {
  __shared__ int off;
  if (threadIdx.x == 0) {
    int s = 0;
    for (int b = 0; b < (int)blockIdx.x; ++b) s += bsum[b];
    off = s;
  }
  __syncthreads();
  int i = blockIdx.x * 1024 + threadIdx.x;
  if (i < M) counts[i] += off;
}

// ---- pass A3: scatter records into bucket-contiguous regions ---------------
// Each (chunk,bucket) segment written by exactly ONE block => writes to a
// sector are temporally clustered on one XCD => L2 merges to full sectors.
__global__ __launch_bounds__(1024) void kA_scat(const int* __restrict__ src,
                                                const int* __restrict__ dst,
                                                const float* __restrict__ w,
                                                const unsigned short* __restrict__ rank,
                                                const int* __restrict__ counts,
                                                unsigned long long* __restrict__ rec,
                                                unsigned char* __restrict__ dl,
                                                int E, int chsz, int nbuk) {
  __shared__ int lh[MAXBUK];
  const int b = blockIdx.x, t = threadIdx.x;
  for (int i = t; i < nbuk; i += 1024) lh[i] = counts[(size_t)i * NCH + b];
  __syncthreads();
  const int e0 = b * chsz, e1 = min(e0 + chsz, E);
  for (int e = e0 + t; e < e1; e += 1024) {
    int d = dst[e];
    int pos = lh[d >> SHIFT] + (int)rank[e];
    rec[pos] = ((unsigned long long)(unsigned)__float_as_int(w[e]) << 32) |
               (unsigned)src[e];
    dl[pos] = (unsigned char)(d & (BWID - 1));
  }
}

// ---- pass B: per-bucket counting sort in LDS -> final CSR + cnt/cursor/dinv
__global__ __launch_bounds__(1024) void kB_sort(const unsigned long long* __restrict__ rec,
                                                const unsigned char* __restrict__ dl,
                                                const int* __restrict__ counts,
                                                unsigned long long* __restrict__ sorted,
                                                int* __restrict__ cnt,
                                                int* __restrict__ cursor,
                                                float* __restrict__ dinv,
                                                int E, int nbuk, int N) {
  __shared__ unsigned h[BWID];
  __shared__ unsigned pf[BWID];
  __shared__ unsigned cur[BWID];
  __shared__ float dg[BWID];
  const int B = blockIdx.x, t = threadIdx.x;
  const int bb = counts[(size_t)B * NCH];
  const int be = (B + 1 < nbuk) ? counts[(size_t)(B + 1) * NCH] : E;
  if (t < BWID) { h[t] = 0u; dg[t] = 0.0f; }
  __syncthreads();
  for (int i = bb + t; i < be; i += 1024) atomicAdd(&h[dl[i]], 1u);
  __syncthreads();
  if (t < BWID) pf[t] = h[t];
  __syncthreads();
  for (int off = 1; off < BWID; off <<= 1) {
    unsigned a = (t >= off && t < BWID) ? pf[t - off] : 0u;
    __syncthreads();
    if (t < BWID) pf[t] += a;
    __syncthreads();
  }
  if (t < BWID) cur[t] = pf[t] - h[t];       // exclusive prefix
  __syncthreads();
  for (int i = bb + t; i < be; i += 1024) {
    unsigned long long r = rec[i];
    int d = dl[i];
    unsigned pos = atomicAdd(&cur[d], 1u);
    sorted[(size_t)bb + pos] = r;            // 32 KB window, one XCD: merges
    atomicAdd(&dg[d], __uint_as_float((unsigned)(r >> 32)));
  }
  __syncthreads();
  const int node = (B << SHIFT) + t;
  if (t < BWID && node < N) {
    cnt[node] = (int)h[t];
    cursor[node] = bb + (int)(pf[t] - h[t]);
    dinv[node] = rsqrtf(1.0f + dg[t]);       // +1 = self loop weight
  }
}

// ---------------- h = x @ W, output bf16 (N x 128)@(128 x 64) ---------------
__global__ __launch_bounds__(256) void k_gemm(const float* __restrict__ x,
                                              const float* __restrict__ W,
                                              unsigned short* __restrict__ hb, int N) {
  __shared__ float Ws[F * H];
  __shared__ float xs[NB * XS_STRIDE];
  const int t = threadIdx.x;
  {
    const float4* W4 = (const float4*)W;
    float4* Ws4 = (float4*)Ws;
#pragma unroll
    for (int i = 0; i < (F * H / 4) / 256; ++i) Ws4[t + i * 256] = W4[t + i * 256];
  }
  const int node0 = blockIdx.x * NB;
  {
    const float4* x4 = (const float4*)(x + (size_t)node0 * F);
    int lim = (N - node0 < NB ? N - node0 : NB) * (F / 4);
    for (int i = t; i < NB * (F / 4); i += 256) {
      int nl = i / (F / 4), kk = i % (F / 4);
      float4 v = (i < lim) ? x4[i] : make_float4(0.f, 0.f, 0.f, 0.f);
      *(float4*)&xs[nl * XS_STRIDE + kk * 4] = v;
    }
  }
  __syncthreads();
  const int f0 = (t & 15) * 4;
  const int nl0 = (t >> 4) * 2;
  float acc[2][4] = {};
  for (int k = 0; k < F; k += 4) {
    float xr[2][4];
    float wr[4][4];
    *(float4*)&xr[0][0] = *(const float4*)&xs[(nl0 + 0) * XS_STRIDE + k];
    *(float4*)&xr[1][0] = *(const float4*)&xs[(nl0 + 1) * XS_STRIDE + k];
#pragma unroll
    for (int i = 0; i < 4; ++i)
      *(float4*)&wr[i][0] = *(const float4*)&Ws[(k + i) * H + f0];
#pragma unroll
    for (int i = 0; i < 4; ++i)
#pragma unroll
      for (int n = 0; n < 2; ++n)
#pragma unroll
        for (int j = 0; j < 4; ++j)
          acc[n][j] += xr[n][i] * wr[i][j];
  }
#pragma unroll
  for (int n = 0; n < 2; ++n) {
    int node = node0 + nl0 + n;
    if (node < N) {
      ushort4 o;
      o.x = __bfloat16_as_ushort(__float2bfloat16(acc[n][0]));
      o.y = __bfloat16_as_ushort(__float2bfloat16(acc[n][1]));
      o.z = __bfloat16_as_ushort(__float2bfloat16(acc[n][2]));
      o.w = __bfloat16_as_ushort(__float2bfloat16(acc[n][3]));
      *(ushort4*)&hb[(size_t)node * H + f0] = o;
    }
  }
}

// ---- gather-aggregate (bf16 h) + fused relu·dot: 16 lanes/node, 4 nodes/wave
__global__ __launch_bounds__(256) void k_agg(const int2* __restrict__ sorted,
                                             const int* __restrict__ cursor,
                                             const int* __restrict__ cnt,
                                             const float* __restrict__ dinv,
                                             const unsigned short* __restrict__ hb,
                                             const float* __restrict__ b,
                                             const float* __restrict__ fcw,
                                             float* __restrict__ partials, int N) {
  const int wid = threadIdx.x >> 6;
  const int lane = threadIdx.x & 63;
  const int seg = lane >> 4;        // 0..3: node segment within wave
  const int sl = lane & 15;         // lane within segment: 16 x 4 feats
  const int n = blockIdx.x * 16 + wid * 4 + seg;
  float p = 0.0f;
  if (n < N) {
    float dn = dinv[n];
    uint2 rn = *(const uint2*)(hb + ((size_t)n << 6) + (sl << 2));
    float4 bb = ((const float4*)b)[sl];
    float dn2 = dn * dn;
    float ax = bb.x + dn2 * blo(rn.x);
    float ay = bb.y + dn2 * bhi(rn.x);
    float az = bb.z + dn2 * blo(rn.y);
    float aw = bb.w + dn2 * bhi(rn.y);
    int e = cursor[n];
    int end = e + cnt[n];
    for (; e + 1 < end; e += 2) {
      int2 e0 = sorted[e];
      int2 e1 = sorted[e + 1];
      float dv0 = dinv[e0.x];
      float dv1 = dinv[e1.x];
      uint2 r0 = *(const uint2*)(hb + ((size_t)e0.x << 6) + (sl << 2));
      uint2 r1 = *(const uint2*)(hb + ((size_t)e1.x << 6) + (sl << 2));
      float n0 = dn * dv0 * __int_as_float(e0.y);
      float n1 = dn * dv1 * __int_as_float(e1.y);
      ax += n0 * blo(r0.x) + n1 * blo(r1.x);
      ay += n0 * bhi(r0.x) + n1 * bhi(r1.x);
      az += n0 * blo(r0.y) + n1 * blo(r1.y);
      aw += n0 * bhi(r0.y) + n1 * bhi(r1.y);
    }
    if (e < end) {
      int2 e0 = sorted[e];
      float dv0 = dinv[e0.x];
      uint2 r0 = *(const uint2*)(hb + ((size_t)e0.x << 6) + (sl << 2));
      float n0 = dn * dv0 * __int_as_float(e0.y);
      ax += n0 * blo(r0.x);
      ay += n0 * bhi(r0.x);
      az += n0 * blo(r0.y);
      aw += n0 * bhi(r0.y);
    }
    float4 fw = ((const float4*)fcw)[(size_t)n * 16 + sl];
    p = fmaxf(ax, 0.f) * fw.x + fmaxf(ay, 0.f) * fw.y +
        fmaxf(az, 0.f) * fw.z + fmaxf(aw, 0.f) * fw.w;
  }
  p += __shfl_down(p, 8);
  p += __shfl_down(p, 4);
  p += __shfl_down(p, 2);
  p += __shfl_down(p, 1);
  __shared__ float ls[16];
  if (sl == 0) ls[wid * 4 + seg] = p;
  __syncthreads();
  if (threadIdx.x == 0) {
    float s = 0.f;
#pragma unroll
    for (int i = 0; i < 16; ++i) s += ls[i];
    partials[blockIdx.x] = s;
  }
}

// ---------------- final: sum partials, + fc_b, sigmoid ----------------------
__global__ __launch_bounds__(1024) void k_fred(const float* __restrict__ partials,
                                               int M,
                                               const float* __restrict__ fcb,
                                               float* __restrict__ out) {
  const int t = threadIdx.x;
  float s = 0.0f;
  for (int i = t; i < M; i += 1024) s += partials[i];
#pragma unroll
  for (int off = 32; off > 0; off >>= 1) s += __shfl_down(s, off);
  __shared__ float ls[16];
  if ((t & 63) == 0) ls[t >> 6] = s;
  __syncthreads();
  if (t == 0) {
    float tot = 0.0f;
#pragma unroll
    for (int i = 0; i < 16; ++i) tot += ls[i];
    float logit = tot + fcb[0];
    out[0] = 1.0f / (1.0f + expf(-logit));
  }
}

extern "C" void kernel_launch(void* const* d_in, const int* in_sizes, int n_in,
                              void* d_out, int out_size, void* d_ws, size_t ws_size,
                              hipStream_t stream) {
  const float* x      = (const float*)d_in[0];
  const int*   elist  = (const int*)d_in[1];
  const float* eattr  = (const float*)d_in[2];
  const float* conv_w = (const float*)d_in[3];
  const float* conv_b = (const float*)d_in[4];
  const float* fc_w   = (const float*)d_in[5];
  const float* fc_b   = (const float*)d_in[6];
  float* out = (float*)d_out;

  const int N = in_sizes[0] / F;   // 50000
  const int E = in_sizes[2];       // 1,600,000
  const int* src = elist;
  const int* dst = elist + E;

  const int chsz = (E + NCH - 1) / NCH;        // 6250
  const int nbuk = ((N - 1) >> SHIFT) + 1;     // 391
  const int M = nbuk * NCH;                    // 100096
  const int nS = (M + 1023) / 1024;            // 98

  char* wsb = (char*)d_ws;
  unsigned long long* sorted = (unsigned long long*)wsb;       // E*8
  unsigned long long* rec = sorted + E;                        // E*8
  int*   counts = (int*)(rec + E);                             // M*4
  int*   cnt    = counts + M;                                  // N*4
  int*   cursor = cnt + N;                                     // N*4
  float* dinv   = (float*)(cursor + N);                        // N*4
  const int nAgg = (N + 15) / 16;
  float* partials = dinv + N;                                  // nAgg*4
  unsigned short* rank = (unsigned short*)(partials + nAgg);   // E*2
  unsigned short* hb = rank + E;                               // N*H*2
  unsigned char* dl = (unsigned char*)(hb + (size_t)N * H);    // E*1
  int* bsum = (int*)(dl + (size_t)E);                          // nS*4

  kA_hist<<<NCH, 1024, 0, stream>>>(dst, counts, rank, E, chsz, nbuk);
  kS1<<<nS, 1024, 0, stream>>>(counts, bsum, M);
  kS2<<<nS, 1024, 0, stream>>>(counts, bsum, M);
  kA_scat<<<NCH, 1024, 0, stream>>>(src, dst, eattr, rank, counts, rec, dl, E,
                                    chsz, nbuk);
  kB_sort<<<nbuk, 1024, 0, stream>>>(rec, dl, counts, sorted, cnt, cursor, dinv,
                                     E, nbuk, N);
  k_gemm<<<(N + NB - 1) / NB, 256, 0, stream>>>(x, conv_w, hb, N);
  k_agg<<<nAgg, 256, 0, stream>>>((const int2*)sorted, cursor, cnt, dinv, hb,
                                  conv_b, fc_w, partials, N);
  k_fred<<<1, 1024, 0, stream>>>(partials, nAgg, fc_b, out);
}